// Round 5
// baseline (448.204 us; speedup 1.0000x reference)
//
#include <hip/hip_runtime.h>

// Problem constants (fixed by the reference: N=8192, DIM=64, T_ITERS=4).
// T is only available device-side; it controls host launch count, so it is
// hardcoded to the problem's T_ITERS=4.
#define NN 8192
#define DIM 64
#define T_IT 4
#define NPART 8  // spread copies for summ1 atomic accumulation

// Native vector type for __builtin_nontemporal_load (HIP_vector_type is a
// struct and is rejected by the builtin; ext_vector_type is accepted).
typedef float nfloat4 __attribute__((ext_vector_type(4)));

// ---------------------------------------------------------------------------
// Kernel 1: prep. p[d] = sum_k relu(t4[k])*theta3[k][d],
//                 q[d] = sum_k relu(-t4[k])*theta3[k][d].
// Also zeroes the summ slots (3 x 64 for summ2..summ4) and the 8 spread
// copies of summ1 (ws is poisoned to 0xAA before every call).
// ---------------------------------------------------------------------------
__global__ void prep_kernel(const float* __restrict__ theta3,
                            const float* __restrict__ theta4,
                            float* __restrict__ pq,
                            float* __restrict__ summ1_parts,
                            float* __restrict__ summ) {
  const int d = threadIdx.x;  // 64 threads
  float p = 0.f, q = 0.f;
  for (int k = 0; k < DIM; ++k) {
    const float t4 = theta4[k];
    const float th = theta3[k * DIM + d];
    p += fmaxf(t4, 0.f) * th;
    q += fmaxf(-t4, 0.f) * th;
  }
  pq[d] = p;
  pq[DIM + d] = q;
#pragma unroll
  for (int c = 0; c < NPART; ++c) summ1_parts[c * DIM + d] = 0.f;
#pragma unroll
  for (int t = 0; t < T_IT - 1; ++t) summ[t * DIM + d] = 0.f;
}

// ---------------------------------------------------------------------------
// Kernel 2 (BW-dominant, 256 MB read): fused rowsum + scan step 1.
// Since u0 = 0 and summ0 = 0, step 1 collapses to u1 = relu(a + c):
//   sp[i] = sum_j max(g[i,j],0), sn[i] = sum_j max(-g[i,j],0)
//   u1[i][d] = relu(x_i*theta1[d] + sp_i*p[d] + sn_i*q[d])
// 2048 blocks x 256 threads = 8192 waves, EXACTLY one row per wave
// (8 blocks/CU, up to 32 waves/CU for deep HBM request queues).
// Graph is read-once -> nontemporal loads (don't pollute L2).
// summ1 accumulated into 8 spread copies to cut atomic contention.
// ---------------------------------------------------------------------------
__global__ __launch_bounds__(256) void fused_rowsum_step1(
    const float* __restrict__ graph, const int* __restrict__ x,
    const float* __restrict__ theta1, const float* __restrict__ pq,
    float* __restrict__ s_pos, float* __restrict__ s_neg,
    float* __restrict__ u, float* __restrict__ summ1_parts) {
  const int wave = threadIdx.x >> 6;
  const int lane = threadIdx.x & 63;
  const int row = blockIdx.x * 4 + wave;  // 2048*4 == 8192 == NN
  const float pd = pq[lane];
  const float qd = pq[DIM + lane];
  const float t1d = theta1[lane];

  const nfloat4* g = (const nfloat4*)(graph + (size_t)row * NN);
  float sp = 0.f, sn = 0.f;
  for (int it = 0; it < NN / 4 / 64; it += 8) {  // 32 iters, 8 loads in flight
#pragma unroll
    for (int j = 0; j < 8; ++j) {
      const nfloat4 v = __builtin_nontemporal_load(&g[lane + (it + j) * 64]);
      sp += fmaxf(v.x, 0.f) + fmaxf(v.y, 0.f) + fmaxf(v.z, 0.f) + fmaxf(v.w, 0.f);
      sn += fmaxf(-v.x, 0.f) + fmaxf(-v.y, 0.f) + fmaxf(-v.z, 0.f) + fmaxf(-v.w, 0.f);
    }
  }
#pragma unroll
  for (int off = 32; off > 0; off >>= 1) {
    sp += __shfl_down(sp, off);
    sn += __shfl_down(sn, off);
  }
  sp = __shfl(sp, 0);
  sn = __shfl(sn, 0);
  if (lane == 0) {
    s_pos[row] = sp;
    s_neg[row] = sn;
  }
  const float uv = fmaxf((float)x[row] * t1d + sp * pd + sn * qd, 0.f);
  u[(size_t)row * DIM + lane] = uv;

  // block-partial of summ1, one wave-atomic per block into a spread copy
  __shared__ float red[4][DIM];
  red[wave][lane] = uv;
  __syncthreads();
  if (wave == 0)
    atomicAdd(&summ1_parts[(blockIdx.x & (NPART - 1)) * DIM + lane],
              red[0][lane] + red[1][lane] + red[2][lane] + red[3][lane]);
}

// ---------------------------------------------------------------------------
// Kernel 3: scan steps 2..T.
//   u_new[i][d] = relu( acv[i][d] + (summ_in @ th2)[d] - (u[i] @ th2)[d] )
// Restructured for latency: each lane holds theta2's column d in 64 VGPRs
// (loaded once from L2), so the per-row dot needs only 16 broadcast
// ds_read_b128 of the u-row (17 LDS ops/row vs 80 in the old layout) and
// NO __syncthreads in the row loop — waves are fully independent.
// 1024 blocks x 256 threads = 4096 waves, 2 rows per wave, 4 blocks/CU.
// In-place u update is safe (each row touched by exactly one wave).
// ---------------------------------------------------------------------------
__global__ __launch_bounds__(256) void step_kernel(
    const float* __restrict__ theta1, const float* __restrict__ theta2,
    const int* __restrict__ x, const float* __restrict__ s_pos,
    const float* __restrict__ s_neg, const float* __restrict__ pq,
    const float* __restrict__ summ_in, int ncopies,
    float* __restrict__ summ_out, float* __restrict__ u) {
  __shared__ float sin_sh[DIM];
  __shared__ __align__(16) float ulds[4][DIM];
  __shared__ float red[4][DIM];
  const int t = threadIdx.x;
  const int lane = t & 63;
  const int wave = t >> 6;

  // theta2 column for this lane, in registers (64 VGPRs).
  float th2col[DIM];
#pragma unroll
  for (int k = 0; k < DIM; ++k) th2col[k] = theta2[k * DIM + lane];

  // Fold the ncopies spread copies of summ_in.
  if (t < DIM) {
    float s = 0.f;
    for (int c = 0; c < ncopies; ++c) s += summ_in[c * DIM + t];
    sin_sh[t] = s;
  }
  const float pd = pq[lane];
  const float qd = pq[DIM + lane];
  const float t1d = theta1[lane];
  __syncthreads();
  // gd[lane] = (summ_in @ th2)[lane]  -- sin_sh[k] is a broadcast read.
  float gd = 0.f;
#pragma unroll
  for (int k = 0; k < DIM; ++k) gd += sin_sh[k] * th2col[k];

  const int gwave = blockIdx.x * 4 + wave;     // 0..4095
  const int nwaves = gridDim.x * 4;            // 4096
  float acc = 0.f;
  for (int row = gwave; row < NN; row += nwaves) {
    const float uval = u[(size_t)row * DIM + lane];  // coalesced b32
    ulds[wave][lane] = uval;  // per-wave buffer; in-order LDS, no barrier
    float dot = 0.f;
    const float4* ur = (const float4*)ulds[wave];
#pragma unroll
    for (int kk = 0; kk < DIM / 4; ++kk) {  // 16 broadcast ds_read_b128
      const float4 uv = ur[kk];
      dot += uv.x * th2col[4 * kk + 0];
      dot += uv.y * th2col[4 * kk + 1];
      dot += uv.z * th2col[4 * kk + 2];
      dot += uv.w * th2col[4 * kk + 3];
    }
    const float acv = (float)x[row] * t1d + s_pos[row] * pd + s_neg[row] * qd;
    const float val = fmaxf(acv + gd - dot, 0.f);
    u[(size_t)row * DIM + lane] = val;
    acc += val;
  }
  red[wave][lane] = acc;
  __syncthreads();
  if (wave == 0) {
    atomicAdd(&summ_out[lane],
              red[0][lane] + red[1][lane] + red[2][lane] + red[3][lane]);
  }
}

// ---------------------------------------------------------------------------
// Kernel 4: readout. out = relu(concat(summ@theta6, u[v]@theta7)) @ theta5.
// ---------------------------------------------------------------------------
__global__ void final_kernel(const float* __restrict__ theta5,
                             const float* __restrict__ theta6,
                             const float* __restrict__ theta7,
                             const float* __restrict__ summ,
                             const float* __restrict__ u,
                             const int* __restrict__ vptr,
                             float* __restrict__ out) {
  const int t = threadIdx.x;  // 128 threads
  const int d = t & 63;
  float h;
  if (t < DIM) {
    float s = 0.f;
    for (int k = 0; k < DIM; ++k) s += summ[k] * theta6[k * DIM + d];
    h = fmaxf(s, 0.f) * theta5[d];
  } else {
    const int v = *vptr;
    const float* uv = u + (size_t)v * DIM;
    float s = 0.f;
    for (int k = 0; k < DIM; ++k) s += uv[k] * theta7[k * DIM + d];
    h = fmaxf(s, 0.f) * theta5[DIM + d];
  }
  __shared__ float red[128];
  red[t] = h;
  __syncthreads();
  if (t == 0) {
    float s = 0.f;
    for (int i = 0; i < 128; ++i) s += red[i];
    out[0] = s;
  }
}

extern "C" void kernel_launch(void* const* d_in, const int* in_sizes, int n_in,
                              void* d_out, int out_size, void* d_ws, size_t ws_size,
                              hipStream_t stream) {
  const float* graph  = (const float*)d_in[0];
  const int*   x      = (const int*)d_in[1];
  const float* theta1 = (const float*)d_in[2];
  const float* theta2 = (const float*)d_in[3];
  const float* theta3 = (const float*)d_in[4];
  const float* theta4 = (const float*)d_in[5];
  const float* theta5 = (const float*)d_in[6];
  const float* theta6 = (const float*)d_in[7];
  const float* theta7 = (const float*)d_in[8];
  const int*   vptr   = (const int*)d_in[9];
  // d_in[10] = T (device-side; hardcoded T_IT=4 per problem definition)
  float* out = (float*)d_out;

  // Workspace layout (floats):
  //   pq          : [0, 128)
  //   summ1_parts : [128, 128 + 8*64)        -- 8 spread copies of summ1
  //   summ        : [640, 640 + 3*64)        -- summ2..summ4
  //   s_pos       : [832, 832+NN)
  //   s_neg       : [832+NN, 832+2NN)
  //   u           : [832+2NN, 832+2NN+NN*DIM)
  // No memset needed: prep zeroes summ1_parts/summ; s_pos/s_neg/u are fully
  // written by fused_rowsum_step1 before anything reads them.
  float* ws     = (float*)d_ws;
  float* pq     = ws;
  float* parts  = ws + 128;
  float* summ   = ws + 128 + NPART * DIM;
  float* s_pos  = summ + (T_IT - 1) * DIM;
  float* s_neg  = s_pos + NN;
  float* u      = s_neg + NN;

  prep_kernel<<<1, DIM, 0, stream>>>(theta3, theta4, pq, parts, summ);
  fused_rowsum_step1<<<2048, 256, 0, stream>>>(graph, x, theta1, pq,
                                               s_pos, s_neg, u, parts);
  // step 2 folds the 8 spread copies of summ1; steps 3..4 read a single copy
  step_kernel<<<1024, 256, 0, stream>>>(theta1, theta2, x, s_pos, s_neg, pq,
                                        parts, NPART, summ + 0 * DIM, u);
  for (int t = 2; t < T_IT; ++t) {
    step_kernel<<<1024, 256, 0, stream>>>(theta1, theta2, x, s_pos, s_neg, pq,
                                          summ + (t - 2) * DIM, 1,
                                          summ + (t - 1) * DIM, u);
  }
  final_kernel<<<1, 128, 0, stream>>>(theta5, theta6, theta7,
                                      summ + (T_IT - 2) * DIM, u, vptr, out);
}

// Round 6
// 418.036 us; speedup vs baseline: 1.0722x; 1.0722x over previous
//
#include <hip/hip_runtime.h>

// Problem constants (fixed by the reference: N=8192, DIM=64, T_ITERS=4).
// T is only available device-side; it controls host launch count, so it is
// hardcoded to the problem's T_ITERS=4.
#define NN 8192
#define DIM 64
#define T_IT 4
#define NPART 8  // spread copies for summ1 atomic accumulation

// Native vector type for __builtin_nontemporal_load (HIP_vector_type is a
// struct and is rejected by the builtin; ext_vector_type is accepted).
typedef float nfloat4 __attribute__((ext_vector_type(4)));

// ---------------------------------------------------------------------------
// Kernel 1: prep. p[d] = sum_k relu(t4[k])*theta3[k][d],
//                 q[d] = sum_k relu(-t4[k])*theta3[k][d].
// Also zeroes the summ slots (3 x 64 for summ2..summ4) and the 8 spread
// copies of summ1 (ws is poisoned to 0xAA before every call).
// ---------------------------------------------------------------------------
__global__ void prep_kernel(const float* __restrict__ theta3,
                            const float* __restrict__ theta4,
                            float* __restrict__ pq,
                            float* __restrict__ summ1_parts,
                            float* __restrict__ summ) {
  const int d = threadIdx.x;  // 64 threads
  float p = 0.f, q = 0.f;
  for (int k = 0; k < DIM; ++k) {
    const float t4 = theta4[k];
    const float th = theta3[k * DIM + d];
    p += fmaxf(t4, 0.f) * th;
    q += fmaxf(-t4, 0.f) * th;
  }
  pq[d] = p;
  pq[DIM + d] = q;
#pragma unroll
  for (int c = 0; c < NPART; ++c) summ1_parts[c * DIM + d] = 0.f;
#pragma unroll
  for (int t = 0; t < T_IT - 1; ++t) summ[t * DIM + d] = 0.f;
}

// ---------------------------------------------------------------------------
// Kernel 2 (BW-dominant, 256 MB read): fused rowsum + scan step 1.
// Since u0 = 0 and summ0 = 0, step 1 collapses to u1 = relu(a + c):
//   sp[i] = sum_j max(g[i,j],0), sn[i] = sum_j max(-g[i,j],0)
//   u1[i][d] = relu(x_i*theta1[d] + sp_i*p[d] + sn_i*q[d])
// 2048 blocks x 256 threads = 8192 waves, EXACTLY one row per wave
// (8 blocks/CU, up to 32 waves/CU for deep HBM request queues).
// Graph is read-once -> nontemporal loads (don't pollute L2).
// Emits packed per-row scalars sps[row] = {xf, sp, sn, 0} (one dwordx4 for
// the step kernels instead of 3 scalar loads), u1, and summ1 partials into
// 8 spread copies to cut atomic contention.
// ---------------------------------------------------------------------------
__global__ __launch_bounds__(256) void fused_rowsum_step1(
    const float* __restrict__ graph, const int* __restrict__ x,
    const float* __restrict__ theta1, const float* __restrict__ pq,
    float4* __restrict__ sps, float* __restrict__ u,
    float* __restrict__ summ1_parts) {
  const int wave = threadIdx.x >> 6;
  const int lane = threadIdx.x & 63;
  const int row = blockIdx.x * 4 + wave;  // 2048*4 == 8192 == NN
  const float pd = pq[lane];
  const float qd = pq[DIM + lane];
  const float t1d = theta1[lane];

  const nfloat4* g = (const nfloat4*)(graph + (size_t)row * NN);
  float sp = 0.f, sn = 0.f;
  for (int it = 0; it < NN / 4 / 64; it += 8) {  // 32 iters, 8 loads in flight
#pragma unroll
    for (int j = 0; j < 8; ++j) {
      const nfloat4 v = __builtin_nontemporal_load(&g[lane + (it + j) * 64]);
      sp += fmaxf(v.x, 0.f) + fmaxf(v.y, 0.f) + fmaxf(v.z, 0.f) + fmaxf(v.w, 0.f);
      sn += fmaxf(-v.x, 0.f) + fmaxf(-v.y, 0.f) + fmaxf(-v.z, 0.f) + fmaxf(-v.w, 0.f);
    }
  }
#pragma unroll
  for (int off = 32; off > 0; off >>= 1) {
    sp += __shfl_down(sp, off);
    sn += __shfl_down(sn, off);
  }
  sp = __shfl(sp, 0);
  sn = __shfl(sn, 0);
  const float xf = (float)x[row];
  if (lane == 0) sps[row] = make_float4(xf, sp, sn, 0.f);
  const float uv = fmaxf(xf * t1d + sp * pd + sn * qd, 0.f);
  u[(size_t)row * DIM + lane] = uv;

  // block-partial of summ1, one wave-atomic per block into a spread copy
  __shared__ float red[4][DIM];
  red[wave][lane] = uv;
  __syncthreads();
  if (wave == 0)
    atomicAdd(&summ1_parts[(blockIdx.x & (NPART - 1)) * DIM + lane],
              red[0][lane] + red[1][lane] + red[2][lane] + red[3][lane]);
}

// ---------------------------------------------------------------------------
// Kernel 3: scan steps 2..T (R4 structure — theta2 staged in LDS once per
// block, u-row dot via float4 LDS broadcasts; the R5 register-column variant
// regressed +13us/step and was reverted).
//   u_new[i][d] = relu( acv[i][d] + (summ_in @ th2)[d] - (u[i] @ th2)[d] )
// summ_in is the sum of `ncopies` 64-float copies (8 for step 2, 1 after).
// 512 blocks x 256 threads = 4 rows x 64 dims per iter, 4 iters/block
// (2 blocks/CU so the CU has work during the 2 barriers per iteration).
// In-place u update is safe (each row touched by exactly one block).
// ---------------------------------------------------------------------------
__global__ __launch_bounds__(256) void step_kernel(
    const float* __restrict__ theta1, const float* __restrict__ theta2,
    const float4* __restrict__ sps, const float* __restrict__ pq,
    const float* __restrict__ summ_in, int ncopies,
    float* __restrict__ summ_out, float* __restrict__ u) {
  __shared__ float th2[DIM * DIM];  // 16 KB
  __shared__ float sin_sh[DIM];
  __shared__ float gsh[DIM];
  __shared__ __align__(16) float ush[4][DIM];
  __shared__ float red[4][DIM];
  const int t = threadIdx.x;
  const int d = t & 63;
  const int r = t >> 6;  // row-within-group 0..3

  for (int i = t; i < DIM * DIM; i += 256) th2[i] = theta2[i];
  if (t < DIM) {
    float s = 0.f;
    for (int c = 0; c < ncopies; ++c) s += summ_in[c * DIM + t];
    sin_sh[t] = s;
  }
  __syncthreads();
  if (t < DIM) {
    float g = 0.f;
    for (int k = 0; k < DIM; ++k) g += sin_sh[k] * th2[k * DIM + d];
    gsh[d] = g;
  }
  const float pd = pq[d];
  const float qd = pq[DIM + d];
  const float t1d = theta1[d];
  __syncthreads();
  const float gd = gsh[d];

  float acc = 0.f;
  for (int base = blockIdx.x * 4; base < NN; base += gridDim.x * 4) {
    const int row = base + r;
    ush[r][d] = u[(size_t)row * DIM + d];
    __syncthreads();
    float dot = 0.f;
    const float4* ur = (const float4*)ush[r];
#pragma unroll
    for (int kk = 0; kk < DIM / 4; ++kk) {
      const float4 uv = ur[kk];
      dot += uv.x * th2[(4 * kk + 0) * DIM + d];
      dot += uv.y * th2[(4 * kk + 1) * DIM + d];
      dot += uv.z * th2[(4 * kk + 2) * DIM + d];
      dot += uv.w * th2[(4 * kk + 3) * DIM + d];
    }
    const float4 s = sps[row];  // {xf, sp, sn, 0} broadcast dwordx4
    const float acv = s.x * t1d + s.y * pd + s.z * qd;
    float val = fmaxf(acv + gd - dot, 0.f);
    u[(size_t)row * DIM + d] = val;
    acc += val;
    __syncthreads();  // protect ush before next iteration's overwrite
  }
  red[r][d] = acc;
  __syncthreads();
  if (r == 0) {
    atomicAdd(&summ_out[d], red[0][d] + red[1][d] + red[2][d] + red[3][d]);
  }
}

// ---------------------------------------------------------------------------
// Kernel 4: readout. out = relu(concat(summ@theta6, u[v]@theta7)) @ theta5.
// ---------------------------------------------------------------------------
__global__ void final_kernel(const float* __restrict__ theta5,
                             const float* __restrict__ theta6,
                             const float* __restrict__ theta7,
                             const float* __restrict__ summ,
                             const float* __restrict__ u,
                             const int* __restrict__ vptr,
                             float* __restrict__ out) {
  const int t = threadIdx.x;  // 128 threads
  const int d = t & 63;
  float h;
  if (t < DIM) {
    float s = 0.f;
    for (int k = 0; k < DIM; ++k) s += summ[k] * theta6[k * DIM + d];
    h = fmaxf(s, 0.f) * theta5[d];
  } else {
    const int v = *vptr;
    const float* uv = u + (size_t)v * DIM;
    float s = 0.f;
    for (int k = 0; k < DIM; ++k) s += uv[k] * theta7[k * DIM + d];
    h = fmaxf(s, 0.f) * theta5[DIM + d];
  }
  __shared__ float red[128];
  red[t] = h;
  __syncthreads();
  if (t == 0) {
    float s = 0.f;
    for (int i = 0; i < 128; ++i) s += red[i];
    out[0] = s;
  }
}

extern "C" void kernel_launch(void* const* d_in, const int* in_sizes, int n_in,
                              void* d_out, int out_size, void* d_ws, size_t ws_size,
                              hipStream_t stream) {
  const float* graph  = (const float*)d_in[0];
  const int*   x      = (const int*)d_in[1];
  const float* theta1 = (const float*)d_in[2];
  const float* theta2 = (const float*)d_in[3];
  const float* theta3 = (const float*)d_in[4];
  const float* theta4 = (const float*)d_in[5];
  const float* theta5 = (const float*)d_in[6];
  const float* theta6 = (const float*)d_in[7];
  const float* theta7 = (const float*)d_in[8];
  const int*   vptr   = (const int*)d_in[9];
  // d_in[10] = T (device-side; hardcoded T_IT=4 per problem definition)
  float* out = (float*)d_out;

  // Workspace layout (floats):
  //   pq          : [0, 128)
  //   summ1_parts : [128, 128 + 8*64)        -- 8 spread copies of summ1
  //   summ        : [640, 640 + 3*64)        -- summ2..summ4
  //   sps         : [832, 832 + 4*NN)        -- packed {xf, sp, sn, 0}/row
  //   u           : [832+4NN, 832+4NN+NN*DIM)
  // (sps byte offset 832*4 = 3328, 16B-aligned.)
  // No memset needed: prep zeroes summ1_parts/summ; sps/u are fully written
  // by fused_rowsum_step1 before anything reads them.
  float*  ws    = (float*)d_ws;
  float*  pq    = ws;
  float*  parts = ws + 128;
  float*  summ  = ws + 128 + NPART * DIM;
  float4* sps   = (float4*)(ws + 832);
  float*  u     = ws + 832 + 4 * NN;

  prep_kernel<<<1, DIM, 0, stream>>>(theta3, theta4, pq, parts, summ);
  fused_rowsum_step1<<<2048, 256, 0, stream>>>(graph, x, theta1, pq,
                                               sps, u, parts);
  // step 2 folds the 8 spread copies of summ1; steps 3..4 read a single copy
  step_kernel<<<512, 256, 0, stream>>>(theta1, theta2, sps, pq,
                                       parts, NPART, summ + 0 * DIM, u);
  for (int t = 2; t < T_IT; ++t) {
    step_kernel<<<512, 256, 0, stream>>>(theta1, theta2, sps, pq,
                                         summ + (t - 2) * DIM, 1,
                                         summ + (t - 1) * DIM, u);
  }
  final_kernel<<<1, 128, 0, stream>>>(theta5, theta6, theta7,
                                      summ + (T_IT - 2) * DIM, u, vptr, out);
}